// Round 1
// 104.092 us; speedup vs baseline: 1.0368x; 1.0368x over previous
//
#include <hip/hip_runtime.h>
#include <hip/hip_bf16.h>

#define D  16
#define NB 262144
#define NG 20000
#define ZPITCH 20   // dwords per z row in transpose buffer (16 data + 4 pad)

typedef __attribute__((ext_vector_type(8))) _Float16 f16x8;
typedef __attribute__((ext_vector_type(4))) float f32x4;
typedef __attribute__((ext_vector_type(2))) float f32x2;

// pack two f32 -> f16 RNE pair in one dword (lo = a, hi = b)
__device__ __forceinline__ unsigned pack_f16rn(float a, float b) {
    unsigned short ua = __builtin_bit_cast(unsigned short, (_Float16)a);
    unsigned short ub = __builtin_bit_cast(unsigned short, (_Float16)b);
    return (unsigned)ua | ((unsigned)ub << 16);
}

// ---------------------------------------------------------------------------
// Prep kernel, 80 blocks:
//   blocks 0..78 : per-gene MLP table T[g] (one thread per gene)
//   block  79    : build M[n,k,j] = sum_m BD[n,m]*BW[n,m,k]*BW[m,n,j],
//                  repack to a SINGLE f16 MFMA B-fragment table, fold Boff.
// ---------------------------------------------------------------------------
__global__ void __launch_bounds__(256)
prep_kernel(const float* __restrict__ emb,
            const float* __restrict__ W1, const float* __restrict__ b1,
            const float* __restrict__ W2, const float* __restrict__ b2,
            const float* __restrict__ W3, const float* __restrict__ b3,
            const float* __restrict__ BW, const float* __restrict__ BD,
            const float* __restrict__ Wc1, const float* __restrict__ bc1,
            const float* __restrict__ Boff,
            float* __restrict__ T, short* __restrict__ Bh,
            float* __restrict__ bc1p) {
    __shared__ float smem[8704];   // bw[0,4096) | bd[4096,4352) | Mm[4352,8704) pitch 17
    int tid = threadIdx.x;
    int blk = blockIdx.x;

    if (blk < 79) {
        // ---- gene MLP ----
        int g = blk * 256 + tid;
        if (g >= NG) return;
        float h[D], t[D];
        const float4* ep = (const float4*)(emb + (size_t)g * D);
        float4 v0 = ep[0], v1 = ep[1], v2 = ep[2], v3 = ep[3];
        h[0]=v0.x; h[1]=v0.y; h[2]=v0.z; h[3]=v0.w;
        h[4]=v1.x; h[5]=v1.y; h[6]=v1.z; h[7]=v1.w;
        h[8]=v2.x; h[9]=v2.y; h[10]=v2.z; h[11]=v2.w;
        h[12]=v3.x; h[13]=v3.y; h[14]=v3.z; h[15]=v3.w;
        #pragma unroll
        for (int i = 0; i < D; ++i) {
            float a = b1[i];
            #pragma unroll
            for (int d = 0; d < D; ++d) a = fmaf(W1[i * D + d], h[d], a);
            t[i] = fmaxf(a, 0.f);
        }
        #pragma unroll
        for (int i = 0; i < D; ++i) {
            float a = b2[i];
            #pragma unroll
            for (int d = 0; d < D; ++d) a = fmaf(W2[i * D + d], t[d], a);
            h[i] = fmaxf(a, 0.f);
        }
        #pragma unroll
        for (int i = 0; i < D; ++i) {
            float a = b3[i];
            #pragma unroll
            for (int d = 0; d < D; ++d) a = fmaf(W3[i * D + d], h[d], a);
            t[i] = a;
        }
        float4* tp = (float4*)(T + (size_t)g * D);
        tp[0] = make_float4(t[0], t[1], t[2], t[3]);
        tp[1] = make_float4(t[4], t[5], t[6], t[7]);
        tp[2] = make_float4(t[8], t[9], t[10], t[11]);
        tp[3] = make_float4(t[12], t[13], t[14], t[15]);
        return;
    }

    // ---- build block ----
    float* bwS = smem;
    float* bdS = smem + 4096;
    float* MmS = smem + 4352;   // [256][17]: Mm[kk][n] at kk*17+n
    #pragma unroll
    for (int i = 0; i < 16; ++i) bwS[tid + 256 * i] = BW[tid + 256 * i];
    bdS[tid] = BD[tid];
    __syncthreads();

    // thread (n,j): acc[k] = M[n][k][j], vectorized over k via b128 LDS reads
    int n = tid >> 4, j = tid & 15;
    float acc[16];
    #pragma unroll
    for (int k = 0; k < 16; ++k) acc[k] = 0.f;
    #pragma unroll
    for (int m = 0; m < 16; ++m) {
        float sw = bdS[n * 16 + m] * bwS[(m * 16 + n) * 16 + j];
        const f32x4* w1 = (const f32x4*)&bwS[(n * 16 + m) * 16];
        #pragma unroll
        for (int q = 0; q < 4; ++q) {
            f32x4 w = w1[q];
            acc[4 * q + 0] = fmaf(sw, w.x, acc[4 * q + 0]);
            acc[4 * q + 1] = fmaf(sw, w.y, acc[4 * q + 1]);
            acc[4 * q + 2] = fmaf(sw, w.z, acc[4 * q + 2]);
            acc[4 * q + 3] = fmaf(sw, w.w, acc[4 * q + 3]);
        }
    }
    #pragma unroll
    for (int k = 0; k < 16; ++k) MmS[(k * 16 + j) * 17 + n] = acc[k];
    __syncthreads();

    // repack to a single f16 MFMA B-fragment table (same layout as before)
    for (int idx = tid; idx < 512; idx += 256) {
        int s = idx >> 6, lane = idx & 63;
        int q = lane >> 4, nn = lane & 15;
        unsigned hw[4];
        #pragma unroll
        for (int w = 0; w < 4; ++w) {
            int kk0 = s * 32 + q * 8 + 2 * w;
            float v0 = MmS[kk0 * 17 + nn], v1 = MmS[(kk0 + 1) * 17 + nn];
            hw[w] = pack_f16rn(v0, v1);
        }
        ((uint4*)Bh)[idx] = make_uint4(hw[0], hw[1], hw[2], hw[3]);
    }

    if (tid < 16) {
        float a = bc1[tid];
        #pragma unroll
        for (int nn = 0; nn < 16; ++nn) a += Wc1[tid * 16 + nn] * Boff[nn];
        bc1p[tid] = a;
    }
}

// ---------------------------------------------------------------------------
// Main kernel: wave handles 64 rows (4 MFMA tiles).
// Phase 1: cooperative gather — 4 lanes fetch one 64B T-row; global_load_lds
//          direct to LDS, bank-swizzle done by permuting the SOURCE quad
//          (rule: linear LDS dest, inverse-swizzled source, swizzled read).
// Phase 2: A fragment = f16-RTZ(e0*e1) via v_cvt_pkrtz; ONE f16 MFMA per
//          K-slice against the single f16 B table.
// Phase 3: LDS transpose (pitch 20, b128 reads) + pk-vectorized head.
// LDS layout: stg = [wave][row 0..63][32 dwords], quad q of row r stores
// logical quad q ^ (r&7). 32 KB total; zb aliases it after the barrier.
// ---------------------------------------------------------------------------
__global__ void __launch_bounds__(256)
main_kernel(const int* __restrict__ x, const float* __restrict__ phenos,
            const float* __restrict__ T,
            const short* __restrict__ Bh,
            const float* __restrict__ bc1p, const float* __restrict__ Wc1,
            const float* __restrict__ Wc2, const float* __restrict__ bc2,
            float* __restrict__ out) {
    __shared__ float smem[8192];           // 32 KB
    int tid  = threadIdx.x;
    int wave = tid >> 6, lane = tid & 63;
    int quad = lane >> 4, nl = lane & 15;
    long base = (long)blockIdx.x * 256 + wave * 64;
    float* stg = smem + wave * 2048;       // 64 rows x 32 dwords

    // resident B fragments (f16 single table, 4 KB, L1-resident)
    f16x8 bh[8];
    #pragma unroll
    for (int s = 0; s < 8; ++s) bh[s] = ((const f16x8*)Bh)[s * 64 + lane];

    // ---- phase 1: coalesced gather straight to LDS ----
    // instr i deposits lane l's 16B at stg + i*1024B + 16*l
    //   => row = i*8 + (l>>3), LDS quad = l&7, row&7 == l>>3
    // stored logical quad must be (l&7) ^ (l>>3):
    const int h   = lane >> 3;
    const int sq  = (lane & 7) ^ h;        // logical quad this lane fetches
    const int qtr = sq & 3;                // 16B quarter within the gene row
    const int* xw = x + 2 * base;          // flat: x[2r+gene]
    const int goff = 2 * h + (sq >> 2);    // 2*row_ofs + gene
    int gid[8];
    #pragma unroll
    for (int i = 0; i < 8; ++i) gid[i] = xw[i * 16 + goff];   // 1 cache line/instr
    #pragma unroll
    for (int i = 0; i < 8; ++i) {
        const float* src = T + (size_t)(unsigned)gid[i] * 16 + qtr * 4;
        __builtin_amdgcn_global_load_lds(
            (const __attribute__((address_space(1))) unsigned*)src,
            (__attribute__((address_space(3))) unsigned*)(stg + i * 256),
            16, 0, 0);
    }
    // stg is wave-local: no block barrier needed, just drain the LDS-DMA
    asm volatile("s_waitcnt vmcnt(0)" ::: "memory");

    float2 ph = ((const float2*)phenos)[base + lane];

    // ---- phase 2: MFMA tile loop ----
    f32x4 acc[4];
    #pragma unroll
    for (int t = 0; t < 4; ++t) acc[t] = (f32x4){0.f, 0.f, 0.f, 0.f};
    const int par = quad >> 1;          // e0 parity for this quad
    const int b1q = quad & 1;           // e1 half for this quad
    const int nl7 = nl & 7;

    #pragma unroll
    for (int t = 0; t < 4; ++t) {
        const float* rowp = stg + (t * 16 + nl) * 32;
        // ev[s] = e0[2s+par]: logical quad s>>1 -> LDS quad (s>>1)^nl7,
        // within-quad dwords {par, 2+par}
        float ev[8];
        #pragma unroll
        for (int sp = 0; sp < 4; ++sp) {
            const float* qp = rowp + ((sp ^ nl7) << 2) + par;
            ev[2 * sp]     = qp[0];
            ev[2 * sp + 1] = qp[2];
        }
        // e1[eo..eo+7], eo = 8*b1q: logical quads {4+2*b1q, 5+2*b1q}
        f32x4 e1a = *(const f32x4*)(rowp + (((4 + 2 * b1q) ^ nl7) << 2));
        f32x4 e1b = *(const f32x4*)(rowp + (((5 + 2 * b1q) ^ nl7) << 2));
        float2 e1p[4] = {make_float2(e1a.x, e1a.y), make_float2(e1a.z, e1a.w),
                         make_float2(e1b.x, e1b.y), make_float2(e1b.z, e1b.w)};

        #pragma unroll
        for (int s = 0; s < 8; ++s) {
            unsigned aw[4];
            #pragma unroll
            for (int w = 0; w < 4; ++w) {
                f32x2 p = (f32x2){ev[s] * e1p[w].x, ev[s] * e1p[w].y}; // v_pk_mul_f32
                auto cv = __builtin_amdgcn_cvt_pkrtz(p.x, p.y);        // v_cvt_pkrtz_f16_f32
                aw[w] = __builtin_bit_cast(unsigned, cv);
            }
            f16x8 ah = __builtin_bit_cast(f16x8, make_uint4(aw[0], aw[1], aw[2], aw[3]));
            acc[t] = __builtin_amdgcn_mfma_f32_16x16x32_f16(ah, bh[s], acc[t], 0, 0, 0);
        }
    }

    // ---- phase 3: transpose + head ----
    __syncthreads();                     // zb aliases OTHER waves' stg regions
    float* zb = smem + wave * 1280;      // [64][ZPITCH]
    #pragma unroll
    for (int t = 0; t < 4; ++t) {
        #pragma unroll
        for (int reg = 0; reg < 4; ++reg)
            zb[(t * 16 + quad * 4 + reg) * ZPITCH + nl] = acc[t][reg];
    }
    __builtin_amdgcn_wave_barrier();     // wave-local transpose; DS in-order per wave

    const float* zr = zb + lane * ZPITCH;
    f32x4 q0 = *(const f32x4*)(zr + 0);
    f32x4 q1 = *(const f32x4*)(zr + 4);
    f32x4 q2 = *(const f32x4*)(zr + 8);
    f32x4 q3 = *(const f32x4*)(zr + 12);
    f32x2 zv2[8] = {(f32x2){q0.x, q0.y}, (f32x2){q0.z, q0.w},
                    (f32x2){q1.x, q1.y}, (f32x2){q1.z, q1.w},
                    (f32x2){q2.x, q2.y}, (f32x2){q2.z, q2.w},
                    (f32x2){q3.x, q3.y}, (f32x2){q3.z, q3.w}};

    const f32x2* w2 = (const f32x2*)Wc1;   // Wc1 rows are 16 floats, 8B aligned
    float a2 = bc2[0];
    #pragma unroll
    for (int i = 0; i < 16; ++i) {
        f32x2 u2 = (f32x2){0.f, 0.f};
        #pragma unroll
        for (int n2 = 0; n2 < 8; ++n2) u2 += w2[i * 8 + n2] * zv2[n2];  // v_pk_fma_f32
        float u = u2.x + u2.y + bc1p[i];
        u = fmaxf(u, 0.f);
        a2 = fmaf(Wc2[i], u, a2);
    }

    out[base + lane] = ph.x + ph.y + a2;
}

// ---------------------------------------------------------------------------
extern "C" void kernel_launch(void* const* d_in, const int* in_sizes, int n_in,
                              void* d_out, int out_size, void* d_ws, size_t ws_size,
                              hipStream_t stream) {
    const int*   x      = (const int*)  d_in[0];
    const float* phenos = (const float*)d_in[1];
    const float* emb    = (const float*)d_in[2];
    const float* W1     = (const float*)d_in[3];
    const float* b1     = (const float*)d_in[4];
    const float* W2     = (const float*)d_in[5];
    const float* b2     = (const float*)d_in[6];
    const float* W3     = (const float*)d_in[7];
    const float* b3     = (const float*)d_in[8];
    const float* BW     = (const float*)d_in[9];
    const float* BD     = (const float*)d_in[10];
    const float* Boff   = (const float*)d_in[11];
    const float* Wc1    = (const float*)d_in[12];
    const float* bc1    = (const float*)d_in[13];
    const float* Wc2    = (const float*)d_in[14];
    const float* bc2    = (const float*)d_in[15];
    float* out = (float*)d_out;

    // ws layout (bytes): Bh[0,8192) | (unused 8192..16384) | bc1p[16384,16448) | T[16448,+1.28MB)
    char* wsb = (char*)d_ws;
    short* Bh   = (short*)(wsb);
    float* bc1p = (float*)(wsb + 16384);
    float* T    = (float*)(wsb + 16448);   // 64B-aligned: each gene row = one 64B line

    prep_kernel<<<80, 256, 0, stream>>>(emb, W1, b1, W2, b2, W3, b3, BW, BD,
                                        Wc1, bc1, Boff, T, Bh, bc1p);
    main_kernel<<<NB / 256, 256, 0, stream>>>(x, phenos, T, Bh, bc1p, Wc1, Wc2, bc2, out);
}

// Round 3
// 103.502 us; speedup vs baseline: 1.0428x; 1.0057x over previous
//
#include <hip/hip_runtime.h>
#include <hip/hip_bf16.h>

#define D  16
#define NB 262144
#define NG 20000
#define ZPITCH 20   // dwords per z row in transpose buffer (16 data + 4 pad)

typedef __attribute__((ext_vector_type(8))) _Float16 f16x8;
typedef __attribute__((ext_vector_type(4))) float f32x4;
typedef __attribute__((ext_vector_type(2))) float f32x2;

// pack two f32 -> f16 RNE pair in one dword (lo = a, hi = b)
__device__ __forceinline__ unsigned pack_f16rn(float a, float b) {
    unsigned short ua = __builtin_bit_cast(unsigned short, (_Float16)a);
    unsigned short ub = __builtin_bit_cast(unsigned short, (_Float16)b);
    return (unsigned)ua | ((unsigned)ub << 16);
}

// ---------------------------------------------------------------------------
// Prep kernel, 80 blocks:
//   blocks 0..78 : per-gene MLP table T[g] (one thread per gene)
//   block  79    : build M[n,k,j] = sum_m BD[n,m]*BW[n,m,k]*BW[m,n,j],
//                  repack to a SINGLE f16 MFMA B-fragment table, fold Boff.
// ---------------------------------------------------------------------------
__global__ void __launch_bounds__(256)
prep_kernel(const float* __restrict__ emb,
            const float* __restrict__ W1, const float* __restrict__ b1,
            const float* __restrict__ W2, const float* __restrict__ b2,
            const float* __restrict__ W3, const float* __restrict__ b3,
            const float* __restrict__ BW, const float* __restrict__ BD,
            const float* __restrict__ Wc1, const float* __restrict__ bc1,
            const float* __restrict__ Boff,
            float* __restrict__ T, short* __restrict__ Bh,
            float* __restrict__ bc1p) {
    __shared__ float smem[8704];   // bw[0,4096) | bd[4096,4352) | Mm[4352,8704) pitch 17
    int tid = threadIdx.x;
    int blk = blockIdx.x;

    if (blk < 79) {
        // ---- gene MLP ----
        int g = blk * 256 + tid;
        if (g >= NG) return;
        float h[D], t[D];
        const float4* ep = (const float4*)(emb + (size_t)g * D);
        float4 v0 = ep[0], v1 = ep[1], v2 = ep[2], v3 = ep[3];
        h[0]=v0.x; h[1]=v0.y; h[2]=v0.z; h[3]=v0.w;
        h[4]=v1.x; h[5]=v1.y; h[6]=v1.z; h[7]=v1.w;
        h[8]=v2.x; h[9]=v2.y; h[10]=v2.z; h[11]=v2.w;
        h[12]=v3.x; h[13]=v3.y; h[14]=v3.z; h[15]=v3.w;
        #pragma unroll
        for (int i = 0; i < D; ++i) {
            float a = b1[i];
            #pragma unroll
            for (int d = 0; d < D; ++d) a = fmaf(W1[i * D + d], h[d], a);
            t[i] = fmaxf(a, 0.f);
        }
        #pragma unroll
        for (int i = 0; i < D; ++i) {
            float a = b2[i];
            #pragma unroll
            for (int d = 0; d < D; ++d) a = fmaf(W2[i * D + d], t[d], a);
            h[i] = fmaxf(a, 0.f);
        }
        #pragma unroll
        for (int i = 0; i < D; ++i) {
            float a = b3[i];
            #pragma unroll
            for (int d = 0; d < D; ++d) a = fmaf(W3[i * D + d], h[d], a);
            t[i] = a;
        }
        float4* tp = (float4*)(T + (size_t)g * D);
        tp[0] = make_float4(t[0], t[1], t[2], t[3]);
        tp[1] = make_float4(t[4], t[5], t[6], t[7]);
        tp[2] = make_float4(t[8], t[9], t[10], t[11]);
        tp[3] = make_float4(t[12], t[13], t[14], t[15]);
        return;
    }

    // ---- build block ----
    float* bwS = smem;
    float* bdS = smem + 4096;
    float* MmS = smem + 4352;   // [256][17]: Mm[kk][n] at kk*17+n
    #pragma unroll
    for (int i = 0; i < 16; ++i) bwS[tid + 256 * i] = BW[tid + 256 * i];
    bdS[tid] = BD[tid];
    __syncthreads();

    // thread (n,j): acc[k] = M[n][k][j], vectorized over k via b128 LDS reads
    int n = tid >> 4, j = tid & 15;
    float acc[16];
    #pragma unroll
    for (int k = 0; k < 16; ++k) acc[k] = 0.f;
    #pragma unroll
    for (int m = 0; m < 16; ++m) {
        float sw = bdS[n * 16 + m] * bwS[(m * 16 + n) * 16 + j];
        const f32x4* w1 = (const f32x4*)&bwS[(n * 16 + m) * 16];
        #pragma unroll
        for (int q = 0; q < 4; ++q) {
            f32x4 w = w1[q];
            acc[4 * q + 0] = fmaf(sw, w.x, acc[4 * q + 0]);
            acc[4 * q + 1] = fmaf(sw, w.y, acc[4 * q + 1]);
            acc[4 * q + 2] = fmaf(sw, w.z, acc[4 * q + 2]);
            acc[4 * q + 3] = fmaf(sw, w.w, acc[4 * q + 3]);
        }
    }
    #pragma unroll
    for (int k = 0; k < 16; ++k) MmS[(k * 16 + j) * 17 + n] = acc[k];
    __syncthreads();

    // repack to a single f16 MFMA B-fragment table (same layout as before)
    for (int idx = tid; idx < 512; idx += 256) {
        int s = idx >> 6, lane = idx & 63;
        int q = lane >> 4, nn = lane & 15;
        unsigned hw[4];
        #pragma unroll
        for (int w = 0; w < 4; ++w) {
            int kk0 = s * 32 + q * 8 + 2 * w;
            float v0 = MmS[kk0 * 17 + nn], v1 = MmS[(kk0 + 1) * 17 + nn];
            hw[w] = pack_f16rn(v0, v1);
        }
        ((uint4*)Bh)[idx] = make_uint4(hw[0], hw[1], hw[2], hw[3]);
    }

    if (tid < 16) {
        float a = bc1[tid];
        #pragma unroll
        for (int nn = 0; nn < 16; ++nn) a += Wc1[tid * 16 + nn] * Boff[nn];
        bc1p[tid] = a;
    }
}

// ---------------------------------------------------------------------------
// Main kernel: wave handles 64 rows (4 MFMA tiles). ZERO block barriers —
// every LDS structure is wave-private; ordering via per-wave in-order LDS.
// Phase 1: cooperative gather — 4 lanes fetch one 64B T-row straight to LDS;
//          bank-swizzle via permuted SOURCE quad (linear LDS dest).
// Phase 2: split-wait pipeline: vmcnt(4) -> tiles {0,1} -> vmcnt(0) ->
//          tiles {2,3}; A fragment = f16-RTZ(e0*e1); one f16 MFMA / K-slice.
// Phase 3: transpose into the wave's OWN stg slice (no cross-wave alias),
//          then pk-vectorized head.
// ---------------------------------------------------------------------------
#define DO_TILE(t) do {                                                        \
    const float* rowp = stg + ((t) * 16 + nl) * 32;                            \
    float ev[8];                                                               \
    _Pragma("unroll")                                                          \
    for (int sp = 0; sp < 4; ++sp) {                                           \
        const float* qp = rowp + ((sp ^ nl7) << 2) + par;                      \
        ev[2 * sp]     = qp[0];                                                \
        ev[2 * sp + 1] = qp[2];                                                \
    }                                                                          \
    f32x4 e1a = *(const f32x4*)(rowp + (((4 + 2 * b1q) ^ nl7) << 2));          \
    f32x4 e1b = *(const f32x4*)(rowp + (((5 + 2 * b1q) ^ nl7) << 2));          \
    float2 e1p[4] = {make_float2(e1a.x, e1a.y), make_float2(e1a.z, e1a.w),     \
                     make_float2(e1b.x, e1b.y), make_float2(e1b.z, e1b.w)};    \
    _Pragma("unroll")                                                          \
    for (int s = 0; s < 8; ++s) {                                              \
        unsigned aw[4];                                                        \
        _Pragma("unroll")                                                      \
        for (int w = 0; w < 4; ++w) {                                          \
            f32x2 p = (f32x2){ev[s] * e1p[w].x, ev[s] * e1p[w].y};             \
            auto cv = __builtin_amdgcn_cvt_pkrtz(p.x, p.y);                    \
            aw[w] = __builtin_bit_cast(unsigned, cv);                          \
        }                                                                      \
        f16x8 ah = __builtin_bit_cast(f16x8, make_uint4(aw[0], aw[1], aw[2], aw[3])); \
        acc[t] = __builtin_amdgcn_mfma_f32_16x16x32_f16(ah, bh[s], acc[t], 0, 0, 0);  \
    }                                                                          \
} while (0)

__global__ void __launch_bounds__(256)
main_kernel(const int* __restrict__ x, const float* __restrict__ phenos,
            const float* __restrict__ T,
            const short* __restrict__ Bh,
            const float* __restrict__ bc1p, const float* __restrict__ Wc1,
            const float* __restrict__ Wc2, const float* __restrict__ bc2,
            float* __restrict__ out) {
    __shared__ float smem[8192];           // 32 KB: 4 waves x 64 rows x 32 dwords
    int tid  = threadIdx.x;
    int wave = tid >> 6, lane = tid & 63;
    int quad = lane >> 4, nl = lane & 15;
    long base = (long)blockIdx.x * 256 + wave * 64;
    float* stg = smem + wave * 2048;

    // oldest VMEM first: phenos (consumed at the very end)
    float2 ph = ((const float2*)phenos)[base + lane];

    // ---- phase 1: coalesced gather straight to LDS ----
    // instr i deposits lane l's 16B at stg + i*1024B + 16*l
    //   => row = i*8 + (l>>3), LDS quad = l&7; stored logical quad = (l&7)^(l>>3)
    const int h   = lane >> 3;
    const int sq  = (lane & 7) ^ h;        // logical quad this lane fetches
    const int qtr = sq & 3;                // 16B quarter within the gene row
    const int* xw = x + 2 * base;          // flat: x[2r+gene]
    const int goff = 2 * h + (sq >> 2);    // 2*row_ofs + gene
    int gid[8];
    #pragma unroll
    for (int i = 0; i < 8; ++i) gid[i] = xw[i * 16 + goff];   // 1 cache line/instr

    // resident B fragments (f16 single table, 4 KB, L1-resident) — issued in
    // the shadow of the gid loads' latency
    f16x8 bh[8];
    #pragma unroll
    for (int s = 0; s < 8; ++s) bh[s] = ((const f16x8*)Bh)[s * 64 + lane];

    #pragma unroll
    for (int i = 0; i < 8; ++i) {
        const float* src = T + (size_t)(unsigned)gid[i] * 16 + qtr * 4;
        __builtin_amdgcn_global_load_lds(
            (const __attribute__((address_space(1))) unsigned*)src,
            (__attribute__((address_space(3))) unsigned*)(stg + i * 256),
            16, 0, 0);
    }

    // ---- phase 2: split-wait MFMA pipeline ----
    f32x4 acc[4];
    #pragma unroll
    for (int t = 0; t < 4; ++t) acc[t] = (f32x4){0.f, 0.f, 0.f, 0.f};
    const int par = quad >> 1;          // e0 parity for this quad
    const int b1q = quad & 1;           // e1 half for this quad
    const int nl7 = nl & 7;

    // DMAs 4..7 are the 4 youngest VMEM ops => this guarantees DMAs 0..3
    // (tiles 0,1) plus all older loads (gid, bh, ph) have landed.
    asm volatile("s_waitcnt vmcnt(4)" ::: "memory");
    DO_TILE(0);
    DO_TILE(1);
    asm volatile("s_waitcnt vmcnt(0)" ::: "memory");
    DO_TILE(2);
    DO_TILE(3);

    // ---- phase 3: transpose + head (wave-private; no block barrier) ----
    // zb aliases this wave's OWN stg slice (1280 <= 2048 dwords). All phase-2
    // ds_reads precede these ds_writes in program order through the SAME base
    // pointer (compiler must keep order); per-wave LDS pipeline is in-order.
    asm volatile("" ::: "memory");
    float* zb = stg;                     // [64][ZPITCH]
    #pragma unroll
    for (int t = 0; t < 4; ++t) {
        #pragma unroll
        for (int reg = 0; reg < 4; ++reg)
            zb[(t * 16 + quad * 4 + reg) * ZPITCH + nl] = acc[t][reg];
    }
    __builtin_amdgcn_wave_barrier();
    asm volatile("" ::: "memory");

    const float* zr = zb + lane * ZPITCH;
    f32x4 q0 = *(const f32x4*)(zr + 0);
    f32x4 q1 = *(const f32x4*)(zr + 4);
    f32x4 q2 = *(const f32x4*)(zr + 8);
    f32x4 q3 = *(const f32x4*)(zr + 12);
    f32x2 zv2[8] = {(f32x2){q0.x, q0.y}, (f32x2){q0.z, q0.w},
                    (f32x2){q1.x, q1.y}, (f32x2){q1.z, q1.w},
                    (f32x2){q2.x, q2.y}, (f32x2){q2.z, q2.w},
                    (f32x2){q3.x, q3.y}, (f32x2){q3.z, q3.w}};

    const f32x2* w2 = (const f32x2*)Wc1;   // Wc1 rows are 16 floats, 8B aligned
    float a2 = bc2[0];
    #pragma unroll
    for (int i = 0; i < 16; ++i) {
        f32x2 u2 = (f32x2){0.f, 0.f};
        #pragma unroll
        for (int n2 = 0; n2 < 8; ++n2) u2 += w2[i * 8 + n2] * zv2[n2];  // v_pk_fma_f32
        float u = u2.x + u2.y + bc1p[i];
        u = fmaxf(u, 0.f);
        a2 = fmaf(Wc2[i], u, a2);
    }

    out[base + lane] = ph.x + ph.y + a2;
}

// ---------------------------------------------------------------------------
extern "C" void kernel_launch(void* const* d_in, const int* in_sizes, int n_in,
                              void* d_out, int out_size, void* d_ws, size_t ws_size,
                              hipStream_t stream) {
    const int*   x      = (const int*)  d_in[0];
    const float* phenos = (const float*)d_in[1];
    const float* emb    = (const float*)d_in[2];
    const float* W1     = (const float*)d_in[3];
    const float* b1     = (const float*)d_in[4];
    const float* W2     = (const float*)d_in[5];
    const float* b2     = (const float*)d_in[6];
    const float* W3     = (const float*)d_in[7];
    const float* b3     = (const float*)d_in[8];
    const float* BW     = (const float*)d_in[9];
    const float* BD     = (const float*)d_in[10];
    const float* Boff   = (const float*)d_in[11];
    const float* Wc1    = (const float*)d_in[12];
    const float* bc1    = (const float*)d_in[13];
    const float* Wc2    = (const float*)d_in[14];
    const float* bc2    = (const float*)d_in[15];
    float* out = (float*)d_out;

    // ws layout (bytes): Bh[0,8192) | (unused 8192..16384) | bc1p[16384,16448) | T[16448,+1.28MB)
    char* wsb = (char*)d_ws;
    short* Bh   = (short*)(wsb);
    float* bc1p = (float*)(wsb + 16384);
    float* T    = (float*)(wsb + 16448);   // 64B-aligned: each gene row = one 64B line

    prep_kernel<<<80, 256, 0, stream>>>(emb, W1, b1, W2, b2, W3, b3, BW, BD,
                                        Wc1, bc1, Boff, T, Bh, bc1p);
    main_kernel<<<NB / 256, 256, 0, stream>>>(x, phenos, T, Bh, bc1p, Wc1, Wc2, bc2, out);
}